// Round 1
// baseline (1188.895 us; speedup 1.0000x reference)
//
#include <hip/hip_runtime.h>
#include <hip/hip_bf16.h>
#include <stdint.h>

// Encoder: X->(transpose)->QKV GEMMs -> attention(softmax) -> Wx GEMM -> 128-step LSTM
// B=512 T=128 N=256 H=256, all inputs f32, output f32 (B,T,H).
// Strategy: bf16 MFMA everywhere; LSTM with fully CU-resident W_hh (LDS+registers),
// h carried in fp32 with hi/lo bf16 split for the recurrent matmul.

#define DI __device__ __forceinline__

typedef __attribute__((ext_vector_type(8))) short bf16x8;   // 8 bf16 = 4 VGPR (MFMA A/B frag)
typedef __attribute__((ext_vector_type(4))) short short4v;  // 8B
typedef __attribute__((ext_vector_type(4))) float f32x4;    // MFMA C/D frag
typedef __attribute__((ext_vector_type(4))) int int4v;      // 16B

union U8 { bf16x8 v; short4v h[2]; };

DI unsigned short f2bf(float x){
  union { float f; unsigned u; } v; v.f = x;
  unsigned r = v.u + 0x7fffu + ((v.u >> 16) & 1u);
  return (unsigned short)(r >> 16);
}
DI float bf2f(unsigned short x){
  union { unsigned u; float f; } v; v.u = ((unsigned)x) << 16; return v.f;
}
DI float rcp_(float x){ return __builtin_amdgcn_rcpf(x); }
DI float sigm(float x){ return rcp_(1.0f + __expf(-x)); }
DI float tanhf_(float x){ return 1.0f - 2.0f * rcp_(1.0f + __expf(2.0f * x)); }

#define BB 512
#define TT 128
#define NN 256
#define HH 256

// ---------------------------------------------------------------------------
// K0: cast weights to bf16, fuse biases
__global__ void k_prep(const float* __restrict__ Wq, const float* __restrict__ Wk,
                       const float* __restrict__ Wv, const float* __restrict__ Wih,
                       const float* __restrict__ Whh, const float* __restrict__ bih,
                       const float* __restrict__ bhh,
                       unsigned short* __restrict__ wqb, unsigned short* __restrict__ wkb,
                       unsigned short* __restrict__ wvb, unsigned short* __restrict__ wihb,
                       unsigned short* __restrict__ whhb, float* __restrict__ bias){
  int i = blockIdx.x * 256 + threadIdx.x;
  if (i < 16384){ wqb[i] = f2bf(Wq[i]); wkb[i] = f2bf(Wk[i]); wvb[i] = f2bf(Wv[i]); }
  if (i < 262144){ wihb[i] = f2bf(Wih[i]); whhb[i] = f2bf(Whh[i]); }
  if (i < 1024){ bias[i] = bih[i] + bhh[i]; }
}

// ---------------------------------------------------------------------------
// K1: X (B,T,N) f32 -> Xp (B,N,T) bf16   (tile transpose through LDS)
__global__ __launch_bounds__(256) void k_xpose(const float* __restrict__ X,
                                               unsigned short* __restrict__ Xp){
  __shared__ float tile[128][65];
  int b = blockIdx.y, n0 = blockIdx.x * 64;
  int tid = threadIdx.x;
  int nloc = tid & 63, t0 = tid >> 6;
  const float* src = X + (size_t)b * TT * NN + n0 + nloc;
  #pragma unroll
  for (int r = 0; r < 32; ++r){
    int t = r * 4 + t0;
    tile[t][nloc] = src[(size_t)t * NN];
  }
  __syncthreads();
  int tl = tid & 127, nr0 = tid >> 7;
  unsigned short* dst = Xp + ((size_t)b * NN + n0) * TT + tl;
  #pragma unroll
  for (int r = 0; r < 32; ++r){
    int n = r * 2 + nr0;
    dst[(size_t)n * TT] = f2bf(tile[tl][n]);
  }
}

// ---------------------------------------------------------------------------
// K2: Q/K/V = Xp @ W^T per batch.  M=131072 rows, N=128, K=128.  blockIdx.y = mode.
// mode 0: Q (scaled 1/16), 1: K, 2: V written transposed to (B,T,N).
__global__ __launch_bounds__(256) void k_qkv(const unsigned short* __restrict__ Xp,
      const unsigned short* __restrict__ Wqb, const unsigned short* __restrict__ Wkb,
      const unsigned short* __restrict__ Wvb,
      unsigned short* __restrict__ Qo, unsigned short* __restrict__ Ko,
      unsigned short* __restrict__ Vo){
  __shared__ __align__(16) char smem[32768 + 8192];
  unsigned short* Bs = (unsigned short*)smem;            // 128x128 bf16 swz, 32KB
  char* As = smem + 32768;                               // 128x32 bf16 swz, 8KB
  char* Os = smem;                                       // out stage (reuses Bs)
  int mode = blockIdx.y;
  const unsigned short* W = (mode == 0) ? Wqb : ((mode == 1) ? Wkb : Wvb);
  int m0 = blockIdx.x * 128;
  int tid = threadIdx.x;

  // stage W (swizzle: byte = j*256 + ((k*2) ^ ((j&7)<<4)))
  #pragma unroll
  for (int it = 0; it < 16; ++it){
    int c = it * 256 + tid;
    int j = c >> 5;
    int kc = (c & 31) << 2;
    short4v v = *(const short4v*)(W + j * 128 + kc);
    *(short4v*)((char*)Bs + j * 256 + ((kc * 2) ^ ((j & 7) << 4))) = v;
  }

  int lane = tid & 63, wv = tid >> 6;
  int wr = wv >> 1, wc = wv & 1;
  int l15 = lane & 15, g = lane >> 4;
  f32x4 zro = {0.f, 0.f, 0.f, 0.f};
  f32x4 acc[4][4];
  #pragma unroll
  for (int a = 0; a < 4; ++a)
    #pragma unroll
    for (int bq = 0; bq < 4; ++bq) acc[a][bq] = zro;

  int arow = tid >> 1, ahalf = (tid & 1) * 16;  // A stage mapping (32B/thread)
  const unsigned short* Ap = Xp + (size_t)(m0 + arow) * 128;

  for (int ks = 0; ks < 4; ++ks){
    __syncthreads();
    { // stage A tile 128x32, swizzle: byte = row*64 + ((k*2) ^ ((row&7)<<3))
      const unsigned short* s = Ap + ks * 32 + ahalf;
      char* base = As + arow * 64;
      int kb = ahalf * 2;
      int sw = (arow & 7) << 3;
      *(short4v*)(base + ((kb     ) ^ sw)) = *(const short4v*)(s);
      *(short4v*)(base + ((kb +  8) ^ sw)) = *(const short4v*)(s + 4);
      *(short4v*)(base + ((kb + 16) ^ sw)) = *(const short4v*)(s + 8);
      *(short4v*)(base + ((kb + 24) ^ sw)) = *(const short4v*)(s + 12);
    }
    __syncthreads();
    U8 af[4];
    #pragma unroll
    for (int mt = 0; mt < 4; ++mt){
      int ar = wr * 64 + mt * 16 + l15;
      const char* ab = As + ar * 64;
      int sw = (ar & 7) << 3;
      af[mt].h[0] = *(const short4v*)(ab + ((8 * g) ^ sw));
      af[mt].h[1] = *(const short4v*)(ab + ((8 * g + 32) ^ sw));
    }
    #pragma unroll
    for (int nt = 0; nt < 4; ++nt){
      int jr = wc * 64 + nt * 16 + l15;
      const char* bb = (const char*)Bs + jr * 256;
      int kb = ks * 64 + 8 * g, sw = (jr & 7) << 4;
      U8 bf;
      bf.h[0] = *(const short4v*)(bb + (kb ^ sw));
      bf.h[1] = *(const short4v*)(bb + ((kb + 32) ^ sw));
      #pragma unroll
      for (int mt = 0; mt < 4; ++mt)
        acc[mt][nt] = __builtin_amdgcn_mfma_f32_16x16x32_bf16(af[mt].v, bf.v, acc[mt][nt], 0, 0, 0);
    }
  }
  __syncthreads();
  // stage to LDS (coalesced global writes). mode V stores transposed [t][i].
  float scale = (mode == 0) ? 0.0625f : 1.0f;
  #pragma unroll
  for (int mt = 0; mt < 4; ++mt)
    #pragma unroll
    for (int nt = 0; nt < 4; ++nt)
      #pragma unroll
      for (int r = 0; r < 4; ++r){
        int row = wr * 64 + mt * 16 + g * 4 + r;
        int col = wc * 64 + nt * 16 + l15;
        unsigned short hv = f2bf(acc[mt][nt][r] * scale);
        int addr = (mode == 2) ? (col * 256 + ((row * 2) ^ ((col & 7) << 4)))
                               : (row * 256 + ((col * 2) ^ ((row & 7) << 4)));
        *(unsigned short*)(Os + addr) = hv;
      }
  __syncthreads();
  int orow = tid >> 1, oseg = tid & 1;
  const char* srcrow = Os + orow * 256;
  unsigned short* dst;
  if (mode == 2){
    int bq = m0 >> 8, ibase = m0 & 255;
    dst = Vo + ((size_t)bq * 128 + orow) * 256 + ibase + oseg * 64;
  } else {
    dst = ((mode == 0) ? Qo : Ko) + (size_t)(m0 + orow) * 128 + oseg * 64;
  }
  #pragma unroll
  for (int c = 0; c < 8; ++c){
    int kb = oseg * 128 + c * 16;
    *(int4v*)((char*)dst + c * 16) = *(const int4v*)(srcrow + (kb ^ ((orow & 7) << 4)));
  }
}

// ---------------------------------------------------------------------------
// K3: fused attention per (b, 64-row i-tile). S=QK^T, softmax, Xa^T = V^T P^T.
__global__ __launch_bounds__(256) void k_attn(const unsigned short* __restrict__ Q,
        const unsigned short* __restrict__ K, const unsigned short* __restrict__ Vt,
        unsigned short* __restrict__ Xa){
  __shared__ __align__(16) char smem[16384 + 65536 + 32768 + 256];
  char* Qs = smem;                       // 64 x 128 bf16, 256B rows, swz (i&7)<<4
  char* Ks = smem + 16384;               // 256 x 128 bf16, 256B rows, swz (j&7)<<4 (later: Vs 128x256)
  char* Ps = smem + 16384 + 65536;       // 64 x 256 bf16, 512B rows, swz (i&7)<<4
  float* rden = (float*)(smem + 16384 + 65536 + 32768);
  int b = blockIdx.y, i0 = blockIdx.x * 64;
  int tid = threadIdx.x, lane = tid & 63, wv = tid >> 6;
  int l15 = lane & 15, g = lane >> 4;

  { // stage Q tile (64 rows x 256B)
    int row = tid >> 2, q = tid & 3;
    const char* src = (const char*)(Q + ((size_t)b * 256 + i0 + row) * 128) + q * 64;
    char* dstr = Qs + row * 256;
    int sw = (row & 7) << 4;
    #pragma unroll
    for (int c = 0; c < 4; ++c){
      int kb = q * 64 + c * 16;
      *(int4v*)(dstr + (kb ^ sw)) = *(const int4v*)(src + c * 16);
    }
  }
  { // stage K full (256 rows x 256B)
    const char* src = (const char*)(K + ((size_t)b * 256 + tid) * 128);
    char* dstr = Ks + tid * 256;
    int sw = (tid & 7) << 4;
    #pragma unroll
    for (int c = 0; c < 16; ++c)
      *(int4v*)(dstr + ((c * 16) ^ sw)) = *(const int4v*)(src + c * 16);
  }
  __syncthreads();

  // S = Q K^T : wave owns 16 q-rows, all 256 j
  f32x4 zro = {0.f, 0.f, 0.f, 0.f};
  f32x4 acc[16];
  #pragma unroll
  for (int nt = 0; nt < 16; ++nt) acc[nt] = zro;
  #pragma unroll
  for (int kk = 0; kk < 4; ++kk){
    int ar = wv * 16 + l15;
    const char* ab = Qs + ar * 256;
    int kb = kk * 64 + 8 * g, swa = (ar & 7) << 4;
    U8 a;
    a.h[0] = *(const short4v*)(ab + (kb ^ swa));
    a.h[1] = *(const short4v*)(ab + ((kb + 32) ^ swa));
    #pragma unroll
    for (int nt = 0; nt < 16; ++nt){
      int jr = nt * 16 + l15;
      const char* bb = Ks + jr * 256;
      int swb = (jr & 7) << 4;
      U8 bf;
      bf.h[0] = *(const short4v*)(bb + (kb ^ swb));
      bf.h[1] = *(const short4v*)(bb + ((kb + 32) ^ swb));
      acc[nt] = __builtin_amdgcn_mfma_f32_16x16x32_bf16(a.v, bf.v, acc[nt], 0, 0, 0);
    }
  }
  // softmax over j (rows = wv*16 + 4g + r)
  float mx[4], sm[4];
  #pragma unroll
  for (int r = 0; r < 4; ++r){
    float m = acc[0][r];
    #pragma unroll
    for (int nt = 1; nt < 16; ++nt) m = fmaxf(m, acc[nt][r]);
    #pragma unroll
    for (int s = 1; s < 16; s <<= 1) m = fmaxf(m, __shfl_xor(m, s));
    mx[r] = m;
  }
  #pragma unroll
  for (int r = 0; r < 4; ++r){
    float s = 0.f;
    #pragma unroll
    for (int nt = 0; nt < 16; ++nt){
      float p = __expf(acc[nt][r] - mx[r]);
      acc[nt][r] = p; s += p;
    }
    #pragma unroll
    for (int sd = 1; sd < 16; sd <<= 1) s += __shfl_xor(s, sd);
    sm[r] = s;
  }
  #pragma unroll
  for (int nt = 0; nt < 16; ++nt)
    #pragma unroll
    for (int r = 0; r < 4; ++r){
      int ir = wv * 16 + g * 4 + r;
      *(unsigned short*)(Ps + ir * 512 + ((nt * 16 + l15) * 2 ^ ((ir & 7) << 4))) = f2bf(acc[nt][r]);
    }
  #pragma unroll
  for (int r = 0; r < 4; ++r)
    if (l15 == r) rden[wv * 16 + g * 4 + r] = rcp_(sm[r]);
  __syncthreads();           // all QK reads of Ks done; Ps/rden written
  { // stage Vs (128 rows x 512B) into Ks space
    int row = tid >> 1, half = tid & 1;
    const char* src = (const char*)(Vt + ((size_t)b * 128 + row) * 256) + half * 256;
    char* dstr = Ks + row * 512;
    int sw = (row & 7) << 4;
    #pragma unroll
    for (int c = 0; c < 16; ++c){
      int jb = half * 256 + c * 16;
      *(int4v*)(dstr + (jb ^ sw)) = *(const int4v*)(src + c * 16);
    }
  }
  __syncthreads();

  // Xa^T tile = V^T @ P^T : wave owns 32 t-rows, 64 i-cols
  f32x4 acc2[2][4];
  #pragma unroll
  for (int mt = 0; mt < 2; ++mt)
    #pragma unroll
    for (int nt = 0; nt < 4; ++nt) acc2[mt][nt] = zro;
  #pragma unroll
  for (int kk = 0; kk < 8; ++kk){
    int kb = kk * 64 + 8 * g;
    U8 bfr[4];
    #pragma unroll
    for (int nt = 0; nt < 4; ++nt){
      int ir = nt * 16 + l15;
      const char* pb = Ps + ir * 512;
      int sw = (ir & 7) << 4;
      bfr[nt].h[0] = *(const short4v*)(pb + (kb ^ sw));
      bfr[nt].h[1] = *(const short4v*)(pb + ((kb + 32) ^ sw));
    }
    #pragma unroll
    for (int mt = 0; mt < 2; ++mt){
      int tr = wv * 32 + mt * 16 + l15;
      const char* ab = Ks + tr * 512;
      int sw = (tr & 7) << 4;
      U8 a;
      a.h[0] = *(const short4v*)(ab + (kb ^ sw));
      a.h[1] = *(const short4v*)(ab + ((kb + 32) ^ sw));
      #pragma unroll
      for (int nt = 0; nt < 4; ++nt)
        acc2[mt][nt] = __builtin_amdgcn_mfma_f32_16x16x32_bf16(a.v, bfr[nt].v, acc2[mt][nt], 0, 0, 0);
    }
  }
  #pragma unroll
  for (int nt = 0; nt < 4; ++nt){
    float rd = rden[nt * 16 + l15];
    #pragma unroll
    for (int mt = 0; mt < 2; ++mt)
      #pragma unroll
      for (int r = 0; r < 4; ++r){
        int t = wv * 32 + mt * 16 + g * 4 + r;
        int i = i0 + nt * 16 + l15;
        Xa[((size_t)b * 128 + t) * 256 + i] = f2bf(acc2[mt][nt][r] * rd);
      }
  }
}

// ---------------------------------------------------------------------------
// K4: Wx = Xa @ W_ih^T + bias, written time-major (T,B,4H). M-tile = one batch (128 t).
template<bool WXF32>
__global__ __launch_bounds__(256) void k_wx(const unsigned short* __restrict__ Xa,
        const unsigned short* __restrict__ Wih, const float* __restrict__ bias,
        void* __restrict__ WxT){
  __shared__ __align__(16) char smem[65536 + 8192];
  char* Bsm = smem;          // 128 j-rows x 512B, swz (j&7)<<4
  char* As = smem + 65536;   // 128 x 32 bf16, 64B rows, swz (row&7)<<3
  int bidx = blockIdx.x;
  int j0 = blockIdx.y * 128;
  int tid = threadIdx.x;
  { // stage B panel once
    int row = tid >> 1, half = tid & 1;
    const char* src = (const char*)(Wih + (size_t)(j0 + row) * 256) + half * 256;
    char* dstr = Bsm + row * 512;
    int sw = (row & 7) << 4;
    #pragma unroll
    for (int c = 0; c < 16; ++c){
      int kb = half * 256 + c * 16;
      *(int4v*)(dstr + (kb ^ sw)) = *(const int4v*)(src + c * 16);
    }
  }
  int lane = tid & 63, wv = tid >> 6, wr = wv >> 1, wc = wv & 1;
  int l15 = lane & 15, g = lane >> 4;
  f32x4 zro = {0.f, 0.f, 0.f, 0.f};
  f32x4 acc[4][4];
  #pragma unroll
  for (int a = 0; a < 4; ++a)
    #pragma unroll
    for (int bq = 0; bq < 4; ++bq) acc[a][bq] = zro;
  int arow = tid >> 1, ahalf = (tid & 1) * 16;
  const unsigned short* Ap = Xa + (size_t)(bidx * 128 + arow) * 256;
  for (int ks = 0; ks < 8; ++ks){
    __syncthreads();
    {
      const unsigned short* s = Ap + ks * 32 + ahalf;
      char* base = As + arow * 64;
      int kb = ahalf * 2, sw = (arow & 7) << 3;
      *(short4v*)(base + ((kb     ) ^ sw)) = *(const short4v*)(s);
      *(short4v*)(base + ((kb +  8) ^ sw)) = *(const short4v*)(s + 4);
      *(short4v*)(base + ((kb + 16) ^ sw)) = *(const short4v*)(s + 8);
      *(short4v*)(base + ((kb + 24) ^ sw)) = *(const short4v*)(s + 12);
    }
    __syncthreads();
    U8 af[4];
    #pragma unroll
    for (int mt = 0; mt < 4; ++mt){
      int ar = wr * 64 + mt * 16 + l15;
      const char* ab = As + ar * 64;
      int sw = (ar & 7) << 3;
      af[mt].h[0] = *(const short4v*)(ab + ((8 * g) ^ sw));
      af[mt].h[1] = *(const short4v*)(ab + ((8 * g + 32) ^ sw));
    }
    #pragma unroll
    for (int nt = 0; nt < 4; ++nt){
      int jr = wc * 64 + nt * 16 + l15;
      const char* bb = Bsm + jr * 512;
      int kb = ks * 64 + 8 * g, sw = (jr & 7) << 4;
      U8 bf;
      bf.h[0] = *(const short4v*)(bb + (kb ^ sw));
      bf.h[1] = *(const short4v*)(bb + ((kb + 32) ^ sw));
      #pragma unroll
      for (int mt = 0; mt < 4; ++mt)
        acc[mt][nt] = __builtin_amdgcn_mfma_f32_16x16x32_bf16(af[mt].v, bf.v, acc[mt][nt], 0, 0, 0);
    }
  }
  #pragma unroll
  for (int nt = 0; nt < 4; ++nt){
    int j = j0 + wc * 64 + nt * 16 + l15;
    float bs = bias[j];
    #pragma unroll
    for (int mt = 0; mt < 4; ++mt)
      #pragma unroll
      for (int r = 0; r < 4; ++r){
        int t = wr * 64 + mt * 16 + g * 4 + r;     // local row = time step
        float v = acc[mt][nt][r] + bs;
        size_t o = ((size_t)t * 512 + bidx) * 1024 + j;
        if (WXF32) ((float*)WxT)[o] = v;
        else       ((unsigned short*)WxT)[o] = f2bf(v);
      }
  }
}

// ---------------------------------------------------------------------------
// K5: LSTM. 64 blocks x 512 thr (8 waves), BM=8 batch rows per block, 128 steps.
// W_hh resident: gate i in LDS (128KB swizzled), gates f/g/o in registers (192 VGPR).
// h kept fp32; recurrent matmul uses bf16 hi+lo split. One barrier/step (h dbuf).
template<bool WXF32>
__global__ __launch_bounds__(512, 2) void k_lstm(const void* __restrict__ WxT,
        const unsigned short* __restrict__ Whh, float* __restrict__ out){
  __shared__ __align__(16) char smem[131072 + 16384];
  char* HS = smem + 131072;  // [buf2][hi/lo][8 rows][512B], swz (row&7)<<4
  int tid = threadIdx.x, lane = tid & 63, wv = tid >> 6;
  int l15 = lane & 15, g = lane >> 4;
  int b0 = blockIdx.x * 8;
  bool vrow = (g < 2);

  { // stage gate-i W (rows 0..255 of W_hh) into LDS, swizzled
    int row = tid >> 1, half = tid & 1;
    const char* src = (const char*)(Whh + (size_t)row * 256) + half * 256;
    char* dstr = smem + row * 512;
    int sw = (row & 7) << 4;
    #pragma unroll
    for (int c = 0; c < 16; ++c){
      int kb = half * 256 + c * 16;
      *(int4v*)(dstr + (kb ^ sw)) = *(const int4v*)(src + c * 16);
    }
  }
  { // zero h buffers
    int4v z = {0, 0, 0, 0};
    *(int4v*)(HS + tid * 32) = z;
    *(int4v*)(HS + tid * 32 + 16) = z;
  }
  // register-resident B-fragments for gates f,g,o (this wave's 32 h-cols)
  U8 breg[6][8];
  #pragma unroll
  for (int bt = 0; bt < 6; ++bt){
    int gate = 1 + (bt >> 1), half = bt & 1;
    int j = gate * 256 + wv * 32 + half * 16 + l15;
    const unsigned short* wr_ = Whh + (size_t)j * 256;
    #pragma unroll
    for (int kk = 0; kk < 8; ++kk){
      int k0 = kk * 32 + 4 * g;
      breg[bt][kk].h[0] = *(const short4v*)(wr_ + k0);
      breg[bt][kk].h[1] = *(const short4v*)(wr_ + k0 + 16);
    }
  }
  float cst[2][4];
  #pragma unroll
  for (int h2 = 0; h2 < 2; ++h2)
    #pragma unroll
    for (int r = 0; r < 4; ++r) cst[h2][r] = 0.f;

  // preload Wx for t=0 into accumulators (acc tile = gate*2+half)
  f32x4 acc[8];
  #pragma unroll
  for (int tile = 0; tile < 8; ++tile){
    int gate = tile >> 1, half = tile & 1;
    int j = gate * 256 + wv * 32 + half * 16 + l15;
    #pragma unroll
    for (int r = 0; r < 4; ++r){
      int rw = (g * 4 + r) & 7;
      size_t o = ((size_t)0 * 512 + b0 + rw) * 1024 + j;
      acc[tile][r] = WXF32 ? ((const float*)WxT)[o] : bf2f(((const unsigned short*)WxT)[o]);
    }
  }
  __syncthreads();

  int cur = 0;
  #pragma unroll 1
  for (int t = 0; t < 128; ++t){
    // ---- gates += (h_hi + h_lo) @ W_hh^T
    #pragma unroll
    for (int kk = 0; kk < 8; ++kk){
      int kb = kk * 64 + 8 * g;
      int hrow = l15 & 7;
      const char* hb = HS + cur * 8192 + hrow * 512;
      int hx  = kb ^ (hrow << 4);
      int hx2 = (kb + 32) ^ (hrow << 4);
      U8 ah, al;
      ah.h[0] = *(const short4v*)(hb + hx);
      ah.h[1] = *(const short4v*)(hb + hx2);
      al.h[0] = *(const short4v*)(hb + 4096 + hx);
      al.h[1] = *(const short4v*)(hb + 4096 + hx2);
      #pragma unroll
      for (int half = 0; half < 2; ++half){
        int j = wv * 32 + half * 16 + l15;
        const char* wb = smem + j * 512;
        int sw = (j & 7) << 4;
        U8 bz;
        bz.h[0] = *(const short4v*)(wb + (kb ^ sw));
        bz.h[1] = *(const short4v*)(wb + ((kb + 32) ^ sw));
        acc[half] = __builtin_amdgcn_mfma_f32_16x16x32_bf16(ah.v, bz.v, acc[half], 0, 0, 0);
        acc[half] = __builtin_amdgcn_mfma_f32_16x16x32_bf16(al.v, bz.v, acc[half], 0, 0, 0);
      }
      #pragma unroll
      for (int bt = 0; bt < 6; ++bt){
        acc[2 + bt] = __builtin_amdgcn_mfma_f32_16x16x32_bf16(ah.v, breg[bt][kk].v, acc[2 + bt], 0, 0, 0);
        acc[2 + bt] = __builtin_amdgcn_mfma_f32_16x16x32_bf16(al.v, breg[bt][kk].v, acc[2 + bt], 0, 0, 0);
      }
    }
    // ---- cell update + writes; prefetch next Wx into freed acc tiles
    int nb = cur ^ 1;
    #pragma unroll
    for (int half = 0; half < 2; ++half){
      #pragma unroll
      for (int r = 0; r < 4; ++r){
        float gi = sigm(acc[0 + half][r]);
        float gf = sigm(acc[2 + half][r]);
        float gg = tanhf_(acc[4 + half][r]);
        float go = sigm(acc[6 + half][r]);
        float c = gf * cst[half][r] + gi * gg;
        cst[half][r] = c;
        float h = go * tanhf_(c);
        if (vrow){
          int rw = g * 4 + r;
          int col = wv * 32 + half * 16 + l15;
          out[((size_t)(b0 + rw) * 128 + t) * 256 + col] = h;
          unsigned short hi_ = f2bf(h);
          unsigned short lo_ = f2bf(h - bf2f(hi_));
          int xb = (col * 2) ^ ((rw & 7) << 4);
          *(unsigned short*)(HS + nb * 8192 +        rw * 512 + xb) = hi_;
          *(unsigned short*)(HS + nb * 8192 + 4096 + rw * 512 + xb) = lo_;
        }
      }
      if (t < 127){
        #pragma unroll
        for (int gate = 0; gate < 4; ++gate){
          int tile = gate * 2 + half;
          int j = gate * 256 + wv * 32 + half * 16 + l15;
          #pragma unroll
          for (int r = 0; r < 4; ++r){
            int rw = (g * 4 + r) & 7;
            size_t o = ((size_t)(t + 1) * 512 + b0 + rw) * 1024 + j;
            acc[tile][r] = WXF32 ? ((const float*)WxT)[o] : bf2f(((const unsigned short*)WxT)[o]);
          }
        }
      }
    }
    __syncthreads();
    cur = nb;
  }
}

// ---------------------------------------------------------------------------
extern "C" void kernel_launch(void* const* d_in, const int* in_sizes, int n_in,
                              void* d_out, int out_size, void* d_ws, size_t ws_size,
                              hipStream_t stream){
  (void)in_sizes; (void)n_in; (void)out_size;
  const float* X   = (const float*)d_in[0];
  const float* Wq  = (const float*)d_in[1];
  const float* Wk  = (const float*)d_in[2];
  const float* Wv  = (const float*)d_in[3];
  const float* Wih = (const float*)d_in[4];
  const float* Whh = (const float*)d_in[5];
  const float* bih = (const float*)d_in[6];
  const float* bhh = (const float*)d_in[7];
  float* out = (float*)d_out;
  char* ws = (char*)d_ws;

  const size_t SZ  = 33554432ULL;        // one (B,N,T) bf16 buffer
  const size_t WXF = 268435456ULL;       // Wx f32 (T,B,4H)
  const size_t WTS = 1150976ULL;         // casted weights + bias
  bool wxf32 = ws_size >= WXF + SZ + WTS;
  size_t wxb = wxf32 ? WXF : WXF / 2;

  // Xp/Q/K/Vt overlay the (dead-by-then) Wx region
  unsigned short* p_xp = (unsigned short*)ws;
  unsigned short* p_q  = (unsigned short*)(ws + SZ);
  unsigned short* p_k  = (unsigned short*)(ws + 2 * SZ);
  unsigned short* p_vt = (unsigned short*)(ws + 3 * SZ);
  void* p_wx = (void*)ws;
  char* p = ws + wxb;
  unsigned short* p_xa  = (unsigned short*)p; p += SZ;
  unsigned short* p_wqb = (unsigned short*)p; p += 32768;
  unsigned short* p_wkb = (unsigned short*)p; p += 32768;
  unsigned short* p_wvb = (unsigned short*)p; p += 32768;
  unsigned short* p_wihb= (unsigned short*)p; p += 524288;
  unsigned short* p_whhb= (unsigned short*)p; p += 524288;
  float* p_bias = (float*)p;

  k_prep<<<1024, 256, 0, stream>>>(Wq, Wk, Wv, Wih, Whh, bih, bhh,
                                   p_wqb, p_wkb, p_wvb, p_wihb, p_whhb, p_bias);
  k_xpose<<<dim3(4, 512), 256, 0, stream>>>(X, p_xp);
  k_qkv<<<dim3(1024, 3), 256, 0, stream>>>(p_xp, p_wqb, p_wkb, p_wvb, p_q, p_k, p_vt);
  k_attn<<<dim3(4, 512), 256, 0, stream>>>(p_q, p_k, p_vt, p_xa);
  if (wxf32){
    k_wx<true><<<dim3(512, 8), 256, 0, stream>>>(p_xa, p_wihb, p_bias, p_wx);
    k_lstm<true><<<64, 512, 0, stream>>>(p_wx, p_whhb, out);
  } else {
    k_wx<false><<<dim3(512, 8), 256, 0, stream>>>(p_xa, p_wihb, p_bias, p_wx);
    k_lstm<false><<<64, 512, 0, stream>>>(p_wx, p_whhb, out);
  }
}